// Round 5
// baseline (67.258 us; speedup 1.0000x reference)
//
#include <hip/hip_runtime.h>
#include <math.h>
#include <stdint.h>

#define NROWS 1024
#define DCAT  16384
#define BLK   512
#define NNEG  48
#define CAP   512
#define PCAP  16
// Candidate threshold directly on the 32-bit threefry output:
// rank = bits>>9 >= 2^23 - 98304  <=>  bits >= 0xFD000000.
// P(pass)=1.17%, E[cands/row]~192, sd~13.8 -> P(<48) ~ P(>512) ~ 0.
#define BITS_THR 0xFD000000u

// JAX threefry2x32, key=(0,42), counter=(0,idx), out = x0^x1
// (jax_threefry_partitionable 32-bit path). Verified exact (absmax=0).
__device__ __forceinline__ uint32_t tf_bits(uint32_t idx) {
  const uint32_t ks1 = 42u, ks2 = 0x1BD11BF0u; // 0x1BD11BDA^0^42, ks0=0
  uint32_t x0 = 0u, x1 = idx + ks1;
#define QR(rot) { x0 += x1; x1 = __builtin_rotateleft32(x1, (rot)); x1 ^= x0; }
  QR(13) QR(15) QR(26) QR(6)  x0 += ks1; x1 += ks2 + 1u;
  QR(17) QR(29) QR(16) QR(24) x0 += ks2; x1 += 2u;
  QR(13) QR(15) QR(26) QR(6)              x1 += ks1 + 3u;
  QR(17) QR(29) QR(16) QR(24) x0 += ks1; x1 += ks2 + 4u;
  QR(13) QR(15) QR(26) QR(6)  x0 += ks2; x1 += 5u;
#undef QR
  return x0 ^ x1;
}

// jax.nn.softplus = max(x,0) + log1p(exp(-|x|))
__device__ __forceinline__ float softplus_(float x) {
  return fmaxf(x, 0.f) + log1pf(expf(-fabsf(x)));
}

__global__ __launch_bounds__(BLK, 8) void t2l2_kernel(
    const float* __restrict__ pred, const float* __restrict__ target,
    float* __restrict__ out) {
  const int row = blockIdx.x;
  const int tid = threadIdx.x;
  const float* __restrict__ trow = target + (size_t)row * DCAT;
  const float* __restrict__ prow = pred + (size_t)row * DCAT;
  const float4* __restrict__ t4p = reinterpret_cast<const float4*>(trow);

  __shared__ unsigned long long ckeys[CAP];
  __shared__ int pos_cols[PCAP];
  __shared__ int cnt_s, pcnt_s;
  __shared__ float wsum[BLK / 64];
  if (tid == 0) { cnt_s = 0; pcnt_s = 0; }
  __syncthreads();

  float acc = 0.f;
  const uint32_t base = (uint32_t)row * (uint32_t)DCAT;

  // ---- Phase 1a: stream target (float4), find the 8 positive columns.
  // Pure streaming; branch taken by ~12% of wave-iterations.
  #pragma unroll
  for (int it = 0; it < DCAT / (BLK * 4); ++it) {   // 8 iters
    const int c4 = it * BLK + tid;
    const float4 tv = t4p[c4];
    const uint32_t m = __float_as_uint(tv.x) | __float_as_uint(tv.y) |
                       __float_as_uint(tv.z) | __float_as_uint(tv.w);
    if (m) {                                        // some positive among 4
      const float v[4] = {tv.x, tv.y, tv.z, tv.w};
      #pragma unroll
      for (int j = 0; j < 4; ++j)
        if (v[j] > 0.f) {
          const int p = atomicAdd(&pcnt_s, 1);
          if (p < PCAP) pos_cols[p] = c4 * 4 + j;
        }
    }
  }

  // ---- Phase 1b: pure threefry sweep — ZERO memory ops in the loop.
  // Push high-rank candidates (positivity ignored; filtered in phase 2).
  #pragma unroll 4
  for (int it = 0; it < DCAT / BLK; ++it) {         // 32 iters
    const int col = it * BLK + tid;
    const uint32_t bits = tf_bits(base + (uint32_t)col);
    if (bits >= BITS_THR) {                         // ~1.2% of lanes
      const int p = atomicAdd(&cnt_s, 1);
      if (p < CAP)
        // key: (rank desc, col asc) via one u64 compare; unique per row
        ckeys[p] = ((unsigned long long)(bits >> 9) << 14)
                 | (unsigned long long)(DCAT - 1 - col);
    }
  }
  __syncthreads();

  // ---- Phase 2a: zero out contaminated candidates (positive columns).
  // Row (64 KB) is L2-hot after phase 1a. key=0 sorts below everything.
  const int M = min(cnt_s, CAP);
  for (int i = tid; i < M; i += BLK) {
    const int col = DCAT - 1 - (int)(ckeys[i] & 0x3FFFull);
    if (trow[col] > 0.f) ckeys[i] = 0ull;
  }
  __syncthreads();

  // ---- Phase 2b: exact top-48 by rank-counting (O(M^2), broadcast LDS
  // reads, order-independent) + negative loss.
  for (int i = tid; i < M; i += BLK) {
    const unsigned long long mine = ckeys[i];
    if (mine) {
      int higher = 0;
      for (int j = 0; j < M; ++j) higher += (ckeys[j] > mine) ? 1 : 0;
      if (higher < NNEG) {
        const int col = DCAT - 1 - (int)(mine & 0x3FFFull);
        acc += softplus_(prow[col]);      // negative term: softplus(x)
      }
    }
  }

  // ---- Phase 2c: positive loss (exactly K=8 per row).
  if (tid < min(pcnt_s, PCAP))
    acc += softplus_(-prow[pos_cols[tid]]);

  // Block reduction -> one atomic per block.
  for (int off = 32; off > 0; off >>= 1) acc += __shfl_down(acc, off, 64);
  if ((tid & 63) == 0) wsum[tid >> 6] = acc;
  __syncthreads();
  if (tid == 0) {
    float s = 0.f;
    #pragma unroll
    for (int w = 0; w < BLK / 64; ++w) s += wsum[w];
    atomicAdd(out, s);
  }
}

extern "C" void kernel_launch(void* const* d_in, const int* in_sizes, int n_in,
                              void* d_out, int out_size, void* d_ws, size_t ws_size,
                              hipStream_t stream) {
  const float* pred   = (const float*)d_in[0];
  const float* target = (const float*)d_in[1];
  // d_in[2] = k (int scalar) — compile-time constant 8 in this problem.
  float* out = (float*)d_out;
  hipMemsetAsync(out, 0, sizeof(float), stream);
  t2l2_kernel<<<dim3(NROWS), dim3(BLK), 0, stream>>>(pred, target, out);
}